// Round 1
// baseline (273.702 us; speedup 1.0000x reference)
//
#include <hip/hip_runtime.h>
#include <math.h>

#define Hn 1024
#define Wn 2048
#define Bn 2
#define Cn 3
#define Pn 4
#define EPSf 1e-3f
#define THRf 0.5f
#define W_SEAMf 1.0f
#define W_GRADf 0.5f
#define W_LAPf 0.1f

__device__ __forceinline__ float rl1(float x) {
    return sqrtf(fmaf(x, x, EPSf * EPSf));
}

// One block per (seam p, row h). 256 threads, each owns 4 consecutive columns.
__global__ __launch_bounds__(256) void seam_main(const float* __restrict__ procs,
                                                 const float* __restrict__ mask,
                                                 float* __restrict__ ws) {
    const int p = blockIdx.x / Hn;       // seam 0..2
    const int h = blockIdx.x % Hn;
    const size_t HW = (size_t)Hn * Wn;

    const float* m0row = mask + (size_t)p * HW + (size_t)h * Wn;
    const float* m1row = m0row + HW;
    const size_t baseA = (size_t)p * (Bn * Cn) * HW;  // plane bc=0 of processes[p]
    const size_t dAB   = (size_t)(Bn * Cn) * HW;      // offset processes[p] -> processes[p+1]

    float wsum = 0.f;
    float cnt  = 0.f;

    #pragma unroll
    for (int it = 0; it < 2; ++it) {
        const int w0 = it * 1024 + (int)threadIdx.x * 4;
        const float4 ma = *(const float4*)(m0row + w0);
        const float4 mb = *(const float4*)(m1row + w0);
        bool bb[4];
        bb[0] = (ma.x > THRf) && (mb.x > THRf);
        bb[1] = (ma.y > THRf) && (mb.y > THRf);
        bb[2] = (ma.z > THRf) && (mb.z > THRf);
        bb[3] = (ma.w > THRf) && (mb.w > THRf);
        if (!(bb[0] | bb[1] | bb[2] | bb[3])) continue;

        cnt += (float)bb[0] + (float)bb[1] + (float)bb[2] + (float)bb[3];

        const bool has_d = (h < Hn - 1);
        const bool has_u = (h > 0);

        float sj = 0.f, sg = 0.f, sl = 0.f;
        #pragma unroll
        for (int bc = 0; bc < Bn * Cn; ++bc) {
            const float* A  = procs + baseA + (size_t)bc * HW + (size_t)h * Wn;
            const float* Bp = A + dAB;

            // center row D
            float4 ac = *(const float4*)(A + w0);
            float4 bcv = *(const float4*)(Bp + w0);
            float dc[4] = {ac.x - bcv.x, ac.y - bcv.y, ac.z - bcv.z, ac.w - bcv.w};

            // up / down rows D (zero-padded)
            float du[4] = {0.f, 0.f, 0.f, 0.f};
            float dd[4] = {0.f, 0.f, 0.f, 0.f};
            if (has_u) {
                float4 au = *(const float4*)(A + w0 - Wn);
                float4 bu = *(const float4*)(Bp + w0 - Wn);
                du[0] = au.x - bu.x; du[1] = au.y - bu.y;
                du[2] = au.z - bu.z; du[3] = au.w - bu.w;
            }
            if (has_d) {
                float4 ad = *(const float4*)(A + w0 + Wn);
                float4 bd = *(const float4*)(Bp + w0 + Wn);
                dd[0] = ad.x - bd.x; dd[1] = ad.y - bd.y;
                dd[2] = ad.z - bd.z; dd[3] = ad.w - bd.w;
            }

            // horizontal halo (zero-padded)
            float dl0 = (w0 > 0)        ? (A[w0 - 1] - Bp[w0 - 1]) : 0.f;
            float dr3 = (w0 + 4 < Wn)   ? (A[w0 + 4] - Bp[w0 + 4]) : 0.f;
            float dl[4] = {dl0,   dc[0], dc[1], dc[2]};
            float dr[4] = {dc[1], dc[2], dc[3], dr3};

            #pragma unroll
            for (int e = 0; e < 4; ++e) {
                if (bb[e]) {
                    sj += rl1(dc[e]);
                    // grad_h: x[h+1]-x[h] for h<H-1, else 0; diff of zeros -> rl1(0)=EPS
                    sg += has_d ? rl1(dd[e] - dc[e]) : EPSf;
                    sl += rl1(du[e] + dd[e] + dl[e] + dr[e] - 4.f * dc[e]);
                }
            }
        }
        wsum += W_SEAMf * sj + W_GRADf * sg + W_LAPf * sl;
    }

    // wave-64 shuffle reduction
    #pragma unroll
    for (int off = 32; off > 0; off >>= 1) {
        wsum += __shfl_down(wsum, off, 64);
        cnt  += __shfl_down(cnt,  off, 64);
    }
    __shared__ float swsum[4];
    __shared__ float scnt[4];
    const int wave = threadIdx.x >> 6;
    const int lane = threadIdx.x & 63;
    if (lane == 0) { swsum[wave] = wsum; scnt[wave] = cnt; }
    __syncthreads();
    if (threadIdx.x == 0) {
        float Wt = swsum[0] + swsum[1] + swsum[2] + swsum[3];
        float Ct = scnt[0] + scnt[1] + scnt[2] + scnt[3];
        if (Wt != 0.f || Ct != 0.f) {
            atomicAdd(&ws[p * 2 + 0], Wt);
            atomicAdd(&ws[p * 2 + 1], Ct);
        }
    }
}

__global__ void seam_final(const float* __restrict__ ws, float* __restrict__ out) {
    float acc = 0.f;
    #pragma unroll
    for (int p = 0; p < Pn - 1; ++p) {
        acc += ws[2 * p] / fmaxf(ws[2 * p + 1], EPSf);
    }
    out[0] = acc;
}

extern "C" void kernel_launch(void* const* d_in, const int* in_sizes, int n_in,
                              void* d_out, int out_size, void* d_ws, size_t ws_size,
                              hipStream_t stream) {
    const float* procs = (const float*)d_in[0];  // (P,B,C,H,W) fp32
    const float* mask  = (const float*)d_in[1];  // (P,1,H,W) fp32
    float* wsf = (float*)d_ws;

    hipMemsetAsync(d_ws, 0, 6 * sizeof(float), stream);
    seam_main<<<dim3((Pn - 1) * Hn), dim3(256), 0, stream>>>(procs, mask, wsf);
    seam_final<<<1, 1, 0, stream>>>(wsf, (float*)d_out);
}